// Round 2
// baseline (525.738 us; speedup 1.0000x reference)
//
#include <hip/hip_runtime.h>

#define HW (512 * 512)
#define NBINS 256
#define NB 128                      // batch
#define P1_BLOCKS_X (HW / (256 * 64))   // 16 blocks/batch, 64 px/thread

// ---------------- counts histogram (batch-independent) ----------------
__global__ __launch_bounds__(256) void counts_kernel(const int* __restrict__ bins,
                                                     int* __restrict__ counts) {
    __shared__ int h[NBINS];
    const int tid = threadIdx.x;
    h[tid] = 0;
    __syncthreads();
    // 256 blocks * 256 threads * 1 int4 = HW ints
    int4 v = ((const int4*)bins)[blockIdx.x * 256 + tid];
    if (v.x > 3 && v.x < NBINS) atomicAdd(&h[v.x], 1);
    if (v.y > 3 && v.y < NBINS) atomicAdd(&h[v.y], 1);
    if (v.z > 3 && v.z < NBINS) atomicAdd(&h[v.z], 1);
    if (v.w > 3 && v.w < NBINS) atomicAdd(&h[v.w], 1);
    __syncthreads();
    if (h[tid]) atomicAdd(&counts[tid], h[tid]);
}

// ---------------- pass 1: per-(batch,bin) S1 = sum|n|, S2 = sum n^2 ----------------
__device__ __forceinline__ void px_acc(float p, float q, int bv,
                                       float* __restrict__ s1w, float* __restrict__ s2w) {
    float n = p - q;
    if (bv > 3 && bv < NBINS) {
        atomicAdd(&s1w[bv], fabsf(n));
        atomicAdd(&s2w[bv], n * n);
    }
}

__global__ __launch_bounds__(256, 4) void pass1(const float* __restrict__ parts,
                                                const float* __restrict__ projs,
                                                const int* __restrict__ bins,
                                                float* __restrict__ S1,
                                                float* __restrict__ S2) {
    __shared__ float hist[4][2][NBINS];   // [wave][s1|s2][bin] = 8 KB
    const int tid = threadIdx.x;
    const int wv = tid >> 6;

    float* hz = &hist[0][0][0];
    #pragma unroll
    for (int k = 0; k < 8; ++k) hz[k * 256 + tid] = 0.f;
    __syncthreads();

    const int b = blockIdx.y;
    const float4* __restrict__ p4 = (const float4*)parts + (size_t)b * (HW / 4);
    const float4* __restrict__ q4 = (const float4*)projs + (size_t)b * (HW / 4);
    const int4*  __restrict__ b4 = (const int4*)bins;
    const int blockBase = blockIdx.x * (256 * 64);   // pixels

    float* __restrict__ s1w = hist[wv][0];
    float* __restrict__ s2w = hist[wv][1];

    // 4 chunks of 16 consecutive pixels; all 12 dwordx4 loads batched per chunk
    #pragma unroll
    for (int m = 0; m < 4; ++m) {
        const int f4 = (blockBase + m * (256 * 16) + tid * 16) >> 2;  // float4 index
        float4 P0 = p4[f4 + 0], P1 = p4[f4 + 1], P2 = p4[f4 + 2], P3 = p4[f4 + 3];
        float4 Q0 = q4[f4 + 0], Q1 = q4[f4 + 1], Q2 = q4[f4 + 2], Q3 = q4[f4 + 3];
        int4  B0 = b4[f4 + 0], B1 = b4[f4 + 1], B2 = b4[f4 + 2], B3 = b4[f4 + 3];

        px_acc(P0.x, Q0.x, B0.x, s1w, s2w); px_acc(P0.y, Q0.y, B0.y, s1w, s2w);
        px_acc(P0.z, Q0.z, B0.z, s1w, s2w); px_acc(P0.w, Q0.w, B0.w, s1w, s2w);
        px_acc(P1.x, Q1.x, B1.x, s1w, s2w); px_acc(P1.y, Q1.y, B1.y, s1w, s2w);
        px_acc(P1.z, Q1.z, B1.z, s1w, s2w); px_acc(P1.w, Q1.w, B1.w, s1w, s2w);
        px_acc(P2.x, Q2.x, B2.x, s1w, s2w); px_acc(P2.y, Q2.y, B2.y, s1w, s2w);
        px_acc(P2.z, Q2.z, B2.z, s1w, s2w); px_acc(P2.w, Q2.w, B2.w, s1w, s2w);
        px_acc(P3.x, Q3.x, B3.x, s1w, s2w); px_acc(P3.y, Q3.y, B3.y, s1w, s2w);
        px_acc(P3.z, Q3.z, B3.z, s1w, s2w); px_acc(P3.w, Q3.w, B3.w, s1w, s2w);
    }
    __syncthreads();

    // combine the 4 wave-private histograms, one global atomic per bin per block
    float t1 = hist[0][0][tid] + hist[1][0][tid] + hist[2][0][tid] + hist[3][0][tid];
    float t2 = hist[0][1][tid] + hist[1][1][tid] + hist[2][1][tid] + hist[3][1][tid];
    unsafeAtomicAdd(&S1[b * NBINS + tid], t1);
    unsafeAtomicAdd(&S2[b * NBINS + tid], t2);
}

// ---------------- finalize: per-batch closed-form sum over bins ----------------
__global__ __launch_bounds__(256) void finalize(const float* __restrict__ S1,
                                                const float* __restrict__ S2,
                                                const int* __restrict__ counts,
                                                float* __restrict__ out) {
    const int b = blockIdx.x;
    const int t = threadIdx.x;
    float contrib = 0.f;
    if (t > 3) {   // valid bins are 4..255
        float c = (float)counts[t];
        float s1 = S1[b * NBINS + t];
        float s2 = S2[b * NBINS + t];
        float mean = s1 / fmaxf(c, 1.f);
        float ssq = fmaxf(s2 - mean * s1, 0.f);          // = sum (a - mean)^2
        float var = ssq / fmaxf(c - 1.f, 1.f);
        contrib = -0.5f * s2 / var - c * logf(6.283185307179586f * var);
    }
    #pragma unroll
    for (int off = 32; off > 0; off >>= 1) contrib += __shfl_down(contrib, off, 64);
    __shared__ float w[4];
    if ((t & 63) == 0) w[t >> 6] = contrib;
    __syncthreads();
    if (t == 0) out[b] = w[0] + w[1] + w[2] + w[3];
}

extern "C" void kernel_launch(void* const* d_in, const int* in_sizes, int n_in,
                              void* d_out, int out_size, void* d_ws, size_t ws_size,
                              hipStream_t stream) {
    const float* parts = (const float*)d_in[0];
    const float* projs = (const float*)d_in[1];
    const int* bins    = (const int*)d_in[2];
    float* out = (float*)d_out;

    int*   counts = (int*)d_ws;                       // 256 ints
    float* S1 = (float*)((char*)d_ws + 1024);         // NB*NBINS floats
    float* S2 = S1 + (size_t)NB * NBINS;              // NB*NBINS floats

    size_t zero_bytes = 1024 + 2 * (size_t)NB * NBINS * sizeof(float);
    hipMemsetAsync(d_ws, 0, zero_bytes, stream);

    counts_kernel<<<256, 256, 0, stream>>>(bins, counts);
    pass1<<<dim3(P1_BLOCKS_X, NB), 256, 0, stream>>>(parts, projs, bins, S1, S2);
    finalize<<<NB, 256, 0, stream>>>(S1, S2, counts, out);
}